// Round 3
// baseline (66.197 us; speedup 1.0000x reference)
//
#include <hip/hip_runtime.h>
#include <hip/hip_bf16.h>

#define B_ 8
#define N_ 4096
#define M_ 4096
#define D_ 64
#define BNT (B_ * N_)   // 32768
#define BMT (B_ * M_)   // 32768
#define TA 64           // A band rows per block (held in registers)
#define TB 128          // B tile rows (LDS, double-buffered)
#define CHUNK_TILES 8   // B tiles per block -> 1024-row chunk
#define MCHUNK (M_ / (TB * CHUNK_TILES))  // 4

typedef short bf16x8 __attribute__((ext_vector_type(8)));
typedef float f32x4 __attribute__((ext_vector_type(4)));

__device__ __forceinline__ unsigned short f2bf(float f) {
  __hip_bfloat16 h = __float2bfloat16(f);
  return *reinterpret_cast<unsigned short*>(&h);
}

// Order-preserving float -> uint key for atomicMin/atomicMax(unsigned),
// correct for negative floats too.
__device__ __forceinline__ unsigned fkey(float f) {
  unsigned b = __float_as_uint(f);
  return b ^ ((unsigned)((int)b >> 31) | 0x80000000u);
}
__device__ __forceinline__ float funkey(unsigned k) {
  unsigned b = (k & 0x80000000u) ? (k ^ 0x80000000u) : ~k;
  return __uint_as_float(b);
}

__device__ __forceinline__ void gload_lds16(const void* g, void* l) {
  __builtin_amdgcn_global_load_lds(
      (const __attribute__((address_space(1))) unsigned int*)g,
      (__attribute__((address_space(3))) unsigned int*)l, 16, 0, 0);
}

// Stage a ROWSx64 bf16 tile into XOR-swizzled LDS (row pitch 128B,
// swizzle byte ^= (row&7)<<4). BF: direct global->LDS DMA with
// pre-swizzled per-lane source (m173). !BF: fp32 load + convert + ds_write.
template <int ROWS, bool BF>
__device__ __forceinline__ void stage_tile(const void* gsrc, unsigned short* lds,
                                           int t, int srcpat) {
  if (BF) {
    constexpr int PER_WAVE = (ROWS * 128 / 1024) / 4;  // 1024B chunks per wave
    const char* gp = (const char*)gsrc;
    int w = t >> 6;
#pragma unroll
    for (int i = 0; i < PER_WAVE; i++) {
      int q = w * PER_WAVE + i;
      gload_lds16(gp + q * 1024 + srcpat, (char*)lds + q * 1024);
    }
  } else {
    const float4* g4 = (const float4*)gsrc;
#pragma unroll
    for (int i = 0; i < ROWS * 16 / 256; i++) {
      int off = i * 256 + t;
      float4 v = g4[off];
      int row = off >> 4;
      int cb = (off & 15) * 8;
      int ba = (row * 128 + cb) ^ ((row & 7) << 4);
      ushort4 p;
      p.x = f2bf(v.x); p.y = f2bf(v.y); p.z = f2bf(v.z); p.w = f2bf(v.w);
      *(ushort4*)((char*)lds + ba) = p;
    }
  }
}

// Kernel 1: norms + min-array init (+ optional fp32->bf16 conversion).
template <bool CONV>
__global__ __launch_bounds__(256) void prep_kernel(
    const float* __restrict__ pred, const float* __restrict__ label,
    unsigned short* __restrict__ predbf, unsigned short* __restrict__ labelbf,
    float* __restrict__ x2, float* __restrict__ y2,
    unsigned* __restrict__ minN, unsigned* __restrict__ minM,
    unsigned* __restrict__ gmax) {
  int t = threadIdx.x;
  int lane = t & 15;
  long row = (long)blockIdx.x * 16 + (t >> 4);
  const float4* src;
  unsigned short* bdst;
  float* ndst;
  unsigned* mdst;
  if (row < BNT) {
    src = (const float4*)(pred + row * D_);
    bdst = predbf + row * D_;
    ndst = x2 + row;
    mdst = minN + row;
  } else {
    long r2 = row - BNT;
    src = (const float4*)(label + r2 * D_);
    bdst = labelbf + r2 * D_;
    ndst = y2 + r2;
    mdst = minM + r2;
  }
  float4 v = src[lane];
  if (CONV) {
    ushort4 p;
    p.x = f2bf(v.x); p.y = f2bf(v.y); p.z = f2bf(v.z); p.w = f2bf(v.w);
    *(ushort4*)(bdst + lane * 4) = p;
  }
  float s = v.x * v.x + v.y * v.y + v.z * v.z + v.w * v.w;
  s += __shfl_xor(s, 1);
  s += __shfl_xor(s, 2);
  s += __shfl_xor(s, 4);
  s += __shfl_xor(s, 8);
  if (lane == 0) {
    *ndst = s;
    *mdst = 0xFFFFFFFFu;  // +inf key
  }
  if (blockIdx.x == 0 && t < 2) gmax[t] = 0u;
}

// Kernel 2 (single fused pass): block owns a 64-row A-band (registers) and a
// 1024-row B-chunk (8 double-buffered 128-row LDS tiles). Waves partition the
// B-tile rows (32 each); every wave covers all 64 A-rows. Computes
//   minN[n] via rmin = min_m(y2[m] - 2<a,b>)  (regs across chunk, atomic at end)
//   minM[m] via cmin = min_n(x2[n] - 2<a,b>)  (in-wave reduce, atomic per iter)
template <bool BF>
__global__ __launch_bounds__(256) void fused_kernel(
    const void* __restrict__ Asrc, const void* __restrict__ Bsrc,
    const float* __restrict__ x2g, const float* __restrict__ y2g,
    unsigned* __restrict__ minN, unsigned* __restrict__ minM) {
  __shared__ alignas(16) unsigned short As[TA * 64];
  __shared__ alignas(16) unsigned short Bs[2][TB * 64];
  __shared__ float red[4][TA];

  const int t = threadIdx.x;
  const int b = blockIdx.z;
  const int a0 = blockIdx.x * TA;
  const int tile0 = blockIdx.y * CHUNK_TILES;
  const int w = t >> 6, l = t & 63;
  const int g = l >> 4, c = l & 15;
  const int srcpat = (l >> 3) * 128 + (((l & 7) * 16) ^ ((l >> 3) << 4));

  const size_t rowbytes = BF ? 128 : 256;
  const char* Agl = (const char*)Asrc + ((size_t)b * N_ + a0) * rowbytes;
  const char* Bgl = (const char*)Bsrc + (size_t)b * M_ * rowbytes;

  stage_tile<TA, BF>(Agl, As, t, srcpat);
  stage_tile<TB, BF>(Bgl + (size_t)tile0 * TB * rowbytes, Bs[0], t, srcpat);
  __syncthreads();

  // A fragments: all waves share the full 64-row band.
  bf16x8 af[2][4];
#pragma unroll
  for (int kk = 0; kk < 2; kk++)
#pragma unroll
    for (int mi = 0; mi < 4; mi++) {
      int r = mi * 16 + c;
      int ba = (r * 128 + kk * 64 + g * 16) ^ ((r & 7) << 4);
      af[kk][mi] = *(const bf16x8*)((const char*)As + ba);
    }

  // x2 by output A-row (constant over the whole chunk loop).
  float x2v[4][4];
#pragma unroll
  for (int mi = 0; mi < 4; mi++)
#pragma unroll
    for (int e = 0; e < 4; e++)
      x2v[mi][e] = x2g[(size_t)b * N_ + a0 + mi * 16 + g * 4 + e];

  float rmin[4][4];
#pragma unroll
  for (int mi = 0; mi < 4; mi++)
#pragma unroll
    for (int e = 0; e < 4; e++) rmin[mi][e] = INFINITY;

  for (int it = 0; it < CHUNK_TILES; it++) {
    if (it + 1 < CHUNK_TILES)
      stage_tile<TB, BF>(Bgl + (size_t)(tile0 + it + 1) * TB * rowbytes,
                         Bs[(it + 1) & 1], t, srcpat);
    const char* Bcur = (const char*)Bs[it & 1];
    const int mrow_base = (tile0 + it) * TB + w * 32;

#pragma unroll
    for (int ni = 0; ni < 2; ni++) {
      float nbv = y2g[(size_t)b * M_ + mrow_base + ni * 16 + c];
      int r = w * 32 + ni * 16 + c;
      bf16x8 b0 = *(const bf16x8*)(Bcur + ((r * 128 + g * 16) ^ ((r & 7) << 4)));
      bf16x8 b1 = *(const bf16x8*)(Bcur + ((r * 128 + 64 + g * 16) ^ ((r & 7) << 4)));
      f32x4 acc[4];
#pragma unroll
      for (int mi = 0; mi < 4; mi++)
        acc[mi] = __builtin_amdgcn_mfma_f32_16x16x32_bf16(
            af[0][mi], b0, (f32x4){0.f, 0.f, 0.f, 0.f}, 0, 0, 0);
#pragma unroll
      for (int mi = 0; mi < 4; mi++)
        acc[mi] = __builtin_amdgcn_mfma_f32_16x16x32_bf16(
            af[1][mi], b1, acc[mi], 0, 0, 0);

      float cm = INFINITY;
#pragma unroll
      for (int mi = 0; mi < 4; mi++)
#pragma unroll
        for (int e = 0; e < 4; e++) {
          float m2 = -2.f * acc[mi][e];
          rmin[mi][e] = fminf(rmin[mi][e], m2 + nbv);
          cm = fminf(cm, m2 + x2v[mi][e]);
        }
      cm = fminf(cm, __shfl_xor(cm, 16));
      cm = fminf(cm, __shfl_xor(cm, 32));
      if (g == 0)
        atomicMin(&minM[(size_t)b * M_ + mrow_base + ni * 16 + c], fkey(cm));
    }
    __syncthreads();
  }

  // Row-min finish: reduce over the 16 c-lanes, then across the 4 waves.
#pragma unroll
  for (int mi = 0; mi < 4; mi++)
#pragma unroll
    for (int e = 0; e < 4; e++) {
      float r = rmin[mi][e];
      r = fminf(r, __shfl_xor(r, 1));
      r = fminf(r, __shfl_xor(r, 2));
      r = fminf(r, __shfl_xor(r, 4));
      r = fminf(r, __shfl_xor(r, 8));
      rmin[mi][e] = r;
    }
  if (c == 0) {
#pragma unroll
    for (int mi = 0; mi < 4; mi++)
#pragma unroll
      for (int e = 0; e < 4; e++)
        red[w][mi * 16 + g * 4 + e] = rmin[mi][e];
  }
  __syncthreads();
  if (t < TA) {
    float m = fminf(fminf(red[0][t], red[1][t]), fminf(red[2][t], red[3][t]));
    atomicMin(&minN[(size_t)b * N_ + a0 + t], fkey(m));
  }
}

// Kernel 3: per-slice max of (norm + min), atomicMax into gmax[dir].
__global__ __launch_bounds__(256) void final1_kernel(
    const unsigned* __restrict__ minN, const unsigned* __restrict__ minM,
    const float* __restrict__ x2, const float* __restrict__ y2,
    unsigned* __restrict__ gmax) {
  int dir = blockIdx.x >> 6;
  int blk = blockIdx.x & 63;
  const unsigned* src = dir ? minM : minN;
  const float* nrm = dir ? y2 : x2;
  size_t base = (size_t)blk * 512;
  float mx = -INFINITY;
  for (int i = threadIdx.x; i < 512; i += 256)
    mx = fmaxf(mx, nrm[base + i] + funkey(src[base + i]));
#pragma unroll
  for (int mask = 1; mask < 64; mask <<= 1) mx = fmaxf(mx, __shfl_xor(mx, mask));
  __shared__ float sm[4];
  if ((threadIdx.x & 63) == 0) sm[threadIdx.x >> 6] = mx;
  __syncthreads();
  if (threadIdx.x == 0) {
    mx = fmaxf(fmaxf(sm[0], sm[1]), fmaxf(sm[2], sm[3]));
    atomicMax(&gmax[dir], fkey(mx));
  }
}

__global__ void final2_kernel(const unsigned* __restrict__ gmax, float* __restrict__ out) {
  if (threadIdx.x == 0)
    out[0] = sqrtf(fmaxf(funkey(gmax[0]), 1e-12f)) +
             sqrtf(fmaxf(funkey(gmax[1]), 1e-12f));
}

extern "C" void kernel_launch(void* const* d_in, const int* in_sizes, int n_in,
                              void* d_out, int out_size, void* d_ws, size_t ws_size,
                              hipStream_t stream) {
  const float* pred = (const float*)d_in[0];
  const float* label = (const float*)d_in[1];
  char* ws = (char*)d_ws;

  const size_t bfBytes = (size_t)BNT * D_ * 2;  // 4 MB per array
  const size_t needFast = 2 * bfBytes + (size_t)(BNT + BMT) * 8 + 64;

  if (ws_size >= needFast) {
    unsigned short* predbf = (unsigned short*)ws;
    unsigned short* labelbf = (unsigned short*)(ws + bfBytes);
    float* x2 = (float*)(ws + 2 * bfBytes);
    float* y2 = x2 + BNT;
    unsigned* minN = (unsigned*)(y2 + BMT);
    unsigned* minM = minN + BNT;
    unsigned* gmax = minM + BMT;

    prep_kernel<true><<<(BNT + BMT) / 16, 256, 0, stream>>>(
        pred, label, predbf, labelbf, x2, y2, minN, minM, gmax);
    fused_kernel<true><<<dim3(N_ / TA, MCHUNK, B_), 256, 0, stream>>>(
        predbf, labelbf, x2, y2, minN, minM);
    final1_kernel<<<128, 256, 0, stream>>>(minN, minM, x2, y2, gmax);
    final2_kernel<<<1, 64, 0, stream>>>(gmax, (float*)d_out);
  } else {
    float* x2 = (float*)ws;
    float* y2 = x2 + BNT;
    unsigned* minN = (unsigned*)(y2 + BMT);
    unsigned* minM = minN + BNT;
    unsigned* gmax = minM + BMT;

    prep_kernel<false><<<(BNT + BMT) / 16, 256, 0, stream>>>(
        pred, label, nullptr, nullptr, x2, y2, minN, minM, gmax);
    fused_kernel<false><<<dim3(N_ / TA, MCHUNK, B_), 256, 0, stream>>>(
        pred, label, x2, y2, minN, minM);
    final1_kernel<<<128, 256, 0, stream>>>(minN, minM, x2, y2, gmax);
    final2_kernel<<<1, 64, 0, stream>>>(gmax, (float*)d_out);
  }
}